// Round 2
// baseline (2521.984 us; speedup 1.0000x reference)
//
#include <hip/hip_runtime.h>
#include <hip/hip_bf16.h>

#define TT 2048
#define BB 2
#define CC 1024
#define NH 16
#define HD 64

__device__ __forceinline__ float us2f(unsigned short u) {
    union { unsigned int i; float f; } v; v.i = ((unsigned int)u) << 16; return v.f;
}
__device__ __forceinline__ unsigned short f2us(float f) {
    union { float f; unsigned int i; } v; v.f = f;
    unsigned int i = v.i;
    unsigned int lsb = (i >> 16) & 1u;
    i += 0x7fffu + lsb;           // round-to-nearest-even
    return (unsigned short)(i >> 16);
}

// One wave. For each input: read first 256 ushorts as bf16; genuine bf16 data
// gives 0 "huge/non-finite" hits, fp32-as-ushort gives ~45 hit lanes.
__global__ __launch_bounds__(64) void detect_kernel(
    const void* p0, const void* p1, const void* p2, const void* p3, const void* p4,
    int* flags)
{
    const void* ps[5] = {p0, p1, p2, p3, p4};
    const int lane = threadIdx.x;
    for (int k = 0; k < 5; ++k) {
        const unsigned short* u = (const unsigned short*)ps[k];
        int bad = 0;
        #pragma unroll
        for (int j = 0; j < 4; ++j) {
            float v = us2f(u[lane * 4 + j]);
            if (!(fabsf(v) < 1e4f)) bad = 1;   // NaN compares false -> bad
        }
        unsigned long long m = __ballot(bad != 0);
        if (lane == 0) flags[k] = (__popcll(m) < 4) ? 1 : 0;   // 1 = bf16
    }
}

__device__ __forceinline__ float4 load4(const void* p, size_t i, int isbf) {
    if (isbf) {
        ushort4 u = *reinterpret_cast<const ushort4*>((const unsigned short*)p + i);
        return make_float4(us2f(u.x), us2f(u.y), us2f(u.z), us2f(u.w));
    } else {
        return *reinterpret_cast<const float4*>((const float*)p + i);
    }
}
__device__ __forceinline__ float load1(const void* p, size_t i, int isbf) {
    return isbf ? us2f(((const unsigned short*)p)[i]) : ((const float*)p)[i];
}

// C[M,N] = A[M,K]*B[K,N] + bias[N], fp32 accumulate, dtype-adaptive ends.
// 64x64 tile, BK=16, 256 threads, 4x4 micro-tile.
__global__ __launch_bounds__(256) void gemm_bias(
    const void* __restrict__ A, const void* __restrict__ B,
    const void* __restrict__ bias, void* __restrict__ C,
    int M, int N, int K,
    const int* __restrict__ flags, int afi, int bfi, int biasfi, int cfi)
{
    const int a_bf    = (afi    >= 0) ? flags[afi]    : 0;
    const int b_bf    = (bfi    >= 0) ? flags[bfi]    : 0;
    const int bias_bf = (biasfi >= 0) ? flags[biasfi] : 0;
    const int c_bf    = (cfi    >= 0) ? flags[cfi]    : 0;

    __shared__ float As[16][68];   // [k][m]
    __shared__ float Bs[16][68];   // [k][n]
    const int tid = threadIdx.x;
    const int tx = tid & 15, ty = tid >> 4;
    const int bm = blockIdx.y * 64, bn = blockIdx.x * 64;

    const int la_m = tid >> 2;            // 0..63
    const int la_k = (tid & 3) << 2;      // 0,4,8,12
    const int lb_k = tid >> 4;            // 0..15
    const int lb_n = (tid & 15) << 2;     // 0..60

    float acc[4][4];
    #pragma unroll
    for (int i = 0; i < 4; ++i)
        #pragma unroll
        for (int j = 0; j < 4; ++j) acc[i][j] = 0.f;

    for (int k0 = 0; k0 < K; k0 += 16) {
        float4 ra = load4(A, (size_t)(bm + la_m) * K + k0 + la_k, a_bf);
        float4 rb = load4(B, (size_t)(k0 + lb_k) * N + bn + lb_n, b_bf);
        As[la_k + 0][la_m] = ra.x;
        As[la_k + 1][la_m] = ra.y;
        As[la_k + 2][la_m] = ra.z;
        As[la_k + 3][la_m] = ra.w;
        Bs[lb_k][lb_n + 0] = rb.x;
        Bs[lb_k][lb_n + 1] = rb.y;
        Bs[lb_k][lb_n + 2] = rb.z;
        Bs[lb_k][lb_n + 3] = rb.w;
        __syncthreads();
        #pragma unroll
        for (int kk = 0; kk < 16; ++kk) {
            float a0 = As[kk][ty * 4 + 0];
            float a1 = As[kk][ty * 4 + 1];
            float a2 = As[kk][ty * 4 + 2];
            float a3 = As[kk][ty * 4 + 3];
            float b0 = Bs[kk][tx * 4 + 0];
            float b1 = Bs[kk][tx * 4 + 1];
            float b2 = Bs[kk][tx * 4 + 2];
            float b3 = Bs[kk][tx * 4 + 3];
            acc[0][0] += a0 * b0; acc[0][1] += a0 * b1; acc[0][2] += a0 * b2; acc[0][3] += a0 * b3;
            acc[1][0] += a1 * b0; acc[1][1] += a1 * b1; acc[1][2] += a1 * b2; acc[1][3] += a1 * b3;
            acc[2][0] += a2 * b0; acc[2][1] += a2 * b1; acc[2][2] += a2 * b2; acc[2][3] += a2 * b3;
            acc[3][0] += a3 * b0; acc[3][1] += a3 * b1; acc[3][2] += a3 * b2; acc[3][3] += a3 * b3;
        }
        __syncthreads();
    }

    float bv[4];
    #pragma unroll
    for (int j = 0; j < 4; ++j) bv[j] = load1(bias, bn + tx * 4 + j, bias_bf);

    #pragma unroll
    for (int i = 0; i < 4; ++i) {
        const int row = bm + ty * 4 + i;
        const size_t off = (size_t)row * N + bn + tx * 4;
        float r0 = acc[i][0] + bv[0];
        float r1 = acc[i][1] + bv[1];
        float r2 = acc[i][2] + bv[2];
        float r3 = acc[i][3] + bv[3];
        if (c_bf) {
            alignas(8) unsigned short pk[4];
            pk[0] = f2us(r0); pk[1] = f2us(r1); pk[2] = f2us(r2); pk[3] = f2us(r3);
            *reinterpret_cast<ushort4*>((unsigned short*)C + off) =
                *reinterpret_cast<ushort4*>(pk);
        } else {
            *reinterpret_cast<float4*>((float*)C + off) = make_float4(r0, r1, r2, r3);
        }
    }
}

// Causal flash attention on fp32 qkv ws [B*T, 3C]; writes fp32 y [B*T, C].
// One wave per (bh, 64-query tile); thread = one query row.
__global__ __launch_bounds__(64) void attn(
    const float* __restrict__ qkv, float* __restrict__ y)
{
    __shared__ float Ks[64][68];
    __shared__ float Vs[64][68];
    const int tid = threadIdx.x;
    const int qt = blockIdx.x;          // 0..31
    const int bh = blockIdx.y;          // 0..31
    const int b = bh >> 4, h = bh & 15;
    const int q_idx = qt * 64 + tid;
    const size_t rs = 3 * CC;

    float q[64];
    {
        const float* qrow = qkv + (size_t)(b * TT + q_idx) * rs + h * HD;
        #pragma unroll
        for (int d = 0; d < 64; d += 4) {
            float4 r = *reinterpret_cast<const float4*>(qrow + d);
            q[d + 0] = r.x * 0.125f;   // fold 1/sqrt(64)
            q[d + 1] = r.y * 0.125f;
            q[d + 2] = r.z * 0.125f;
            q[d + 3] = r.w * 0.125f;
        }
    }
    float o[64];
    #pragma unroll
    for (int d = 0; d < 64; ++d) o[d] = 0.f;
    float m_i = -3.0e38f, l_i = 0.f;

    for (int kt = 0; kt <= qt; ++kt) {
        const float* kp = qkv + (size_t)(b * TT + kt * 64 + tid) * rs + CC + h * HD;
        const float* vp = kp + CC;
        #pragma unroll
        for (int d = 0; d < 64; d += 4) {
            float4 rk = *reinterpret_cast<const float4*>(kp + d);
            Ks[tid][d + 0] = rk.x; Ks[tid][d + 1] = rk.y;
            Ks[tid][d + 2] = rk.z; Ks[tid][d + 3] = rk.w;
            float4 rv = *reinterpret_cast<const float4*>(vp + d);
            Vs[tid][d + 0] = rv.x; Vs[tid][d + 1] = rv.y;
            Vs[tid][d + 2] = rv.z; Vs[tid][d + 3] = rv.w;
        }
        __syncthreads();
        const int jmax = (kt == qt) ? (tid + 1) : 64;
        for (int j = 0; j < jmax; ++j) {
            const float4* K4 = reinterpret_cast<const float4*>(&Ks[j][0]);
            float s = 0.f;
            #pragma unroll
            for (int d4 = 0; d4 < 16; ++d4) {
                float4 kv = K4[d4];
                s += q[d4 * 4 + 0] * kv.x + q[d4 * 4 + 1] * kv.y
                   + q[d4 * 4 + 2] * kv.z + q[d4 * 4 + 3] * kv.w;
            }
            float m_new = fmaxf(m_i, s);
            float alpha = __expf(m_i - m_new);
            float p = __expf(s - m_new);
            l_i = l_i * alpha + p;
            const float4* V4 = reinterpret_cast<const float4*>(&Vs[j][0]);
            #pragma unroll
            for (int d4 = 0; d4 < 16; ++d4) {
                float4 vv = V4[d4];
                o[d4 * 4 + 0] = o[d4 * 4 + 0] * alpha + p * vv.x;
                o[d4 * 4 + 1] = o[d4 * 4 + 1] * alpha + p * vv.y;
                o[d4 * 4 + 2] = o[d4 * 4 + 2] * alpha + p * vv.z;
                o[d4 * 4 + 3] = o[d4 * 4 + 3] * alpha + p * vv.w;
            }
            m_i = m_new;
        }
        __syncthreads();
    }

    const float inv = 1.f / l_i;
    float* yrow = y + (size_t)(b * TT + q_idx) * CC + h * HD;
    #pragma unroll
    for (int d = 0; d < 64; d += 4) {
        *reinterpret_cast<float4*>(yrow + d) =
            make_float4(o[d + 0] * inv, o[d + 1] * inv, o[d + 2] * inv, o[d + 3] * inv);
    }
}

extern "C" void kernel_launch(void* const* d_in, const int* in_sizes, int n_in,
                              void* d_out, int out_size, void* d_ws, size_t ws_size,
                              hipStream_t stream) {
    const int M = BB * TT;                      // 4096

    int*   flags = (int*)d_ws;                                  // 5 ints
    float* qkv   = (float*)((char*)d_ws + 256);                 // [4096,3072] f32
    float* y     = (float*)((char*)d_ws + 256 + (size_t)M * 3 * CC * sizeof(float)); // [4096,1024] f32

    detect_kernel<<<1, 64, 0, stream>>>(d_in[0], d_in[1], d_in[2], d_in[3], d_in[4], flags);

    // 1) qkv = x @ W_qkv + b_qkv   (fp32 into ws)
    dim3 g1(3 * CC / 64, M / 64);   // (48, 64)
    gemm_bias<<<g1, 256, 0, stream>>>(d_in[0], d_in[1], d_in[2], qkv,
                                      M, 3 * CC, CC, flags, 0, 1, 2, -1);

    // 2) y = causal_attention(q, k, v)   (fp32 ws -> fp32 ws)
    dim3 g2(TT / 64, BB * NH);      // (32, 32)
    attn<<<g2, 64, 0, stream>>>(qkv, y);

    // 3) out = y @ W_o + b_o   (output dtype = x's dtype)
    dim3 g3(CC / 64, M / 64);       // (16, 64)
    gemm_bias<<<g3, 256, 0, stream>>>(y, d_in[3], d_in[4], d_out,
                                      M, CC, CC, flags, -1, 3, 4, 0);
}

// Round 3
// 725.967 us; speedup vs baseline: 3.4740x; 3.4740x over previous
//
#include <hip/hip_runtime.h>
#include <hip/hip_bf16.h>

#define TT 2048
#define BB 2
#define CC 1024
#define NH 16
#define HD 64

typedef __attribute__((ext_vector_type(8))) short short8;
typedef __attribute__((ext_vector_type(4))) float f32x4;

__device__ __forceinline__ float us2f(unsigned short u) {
    union { unsigned int i; float f; } v; v.i = ((unsigned int)u) << 16; return v.f;
}
__device__ __forceinline__ unsigned short f2us(float f) {
    union { float f; unsigned int i; } v; v.f = f;
    unsigned int i = v.i;
    unsigned int lsb = (i >> 16) & 1u;
    i += 0x7fffu + lsb;           // round-to-nearest-even
    return (unsigned short)(i >> 16);
}

// One wave. For each input: read first 256 ushorts as bf16; genuine bf16 data
// gives 0 "huge/non-finite" hits, fp32-as-ushort gives ~45 hit lanes.
__global__ __launch_bounds__(64) void detect_kernel(
    const void* p0, const void* p1, const void* p2, const void* p3, const void* p4,
    int* flags)
{
    const void* ps[5] = {p0, p1, p2, p3, p4};
    const int lane = threadIdx.x;
    for (int k = 0; k < 5; ++k) {
        const unsigned short* u = (const unsigned short*)ps[k];
        int bad = 0;
        #pragma unroll
        for (int j = 0; j < 4; ++j) {
            float v = us2f(u[lane * 4 + j]);
            if (!(fabsf(v) < 1e4f)) bad = 1;
        }
        unsigned long long m = __ballot(bad != 0);
        if (lane == 0) flags[k] = (__popcll(m) < 4) ? 1 : 0;   // 1 = bf16
    }
}

__device__ __forceinline__ float4 load4(const void* p, size_t i, int isbf) {
    if (isbf) {
        ushort4 u = *reinterpret_cast<const ushort4*>((const unsigned short*)p + i);
        return make_float4(us2f(u.x), us2f(u.y), us2f(u.z), us2f(u.w));
    } else {
        return *reinterpret_cast<const float4*>((const float*)p + i);
    }
}
__device__ __forceinline__ float load1(const void* p, size_t i, int isbf) {
    return isbf ? us2f(((const unsigned short*)p)[i]) : ((const float*)p)[i];
}

// C[M,N] = A[M,K]*B[K,N] + bias[N], fp32 accumulate, dtype-adaptive ends.
// cfi: >=0 -> flags[cfi]; -1 -> fp32 out; -2 -> force bf16 out.
__global__ __launch_bounds__(256) void gemm_bias(
    const void* __restrict__ A, const void* __restrict__ B,
    const void* __restrict__ bias, void* __restrict__ C,
    int M, int N, int K,
    const int* __restrict__ flags, int afi, int bfi, int biasfi, int cfi)
{
    const int a_bf    = (afi    >= 0) ? flags[afi]    : 0;
    const int b_bf    = (bfi    >= 0) ? flags[bfi]    : 0;
    const int bias_bf = (biasfi >= 0) ? flags[biasfi] : 0;
    const int c_bf    = (cfi >= 0) ? flags[cfi] : ((cfi == -2) ? 1 : 0);

    __shared__ float As[16][68];
    __shared__ float Bs[16][68];
    const int tid = threadIdx.x;
    const int tx = tid & 15, ty = tid >> 4;
    const int bm = blockIdx.y * 64, bn = blockIdx.x * 64;

    const int la_m = tid >> 2;
    const int la_k = (tid & 3) << 2;
    const int lb_k = tid >> 4;
    const int lb_n = (tid & 15) << 2;

    float acc[4][4];
    #pragma unroll
    for (int i = 0; i < 4; ++i)
        #pragma unroll
        for (int j = 0; j < 4; ++j) acc[i][j] = 0.f;

    for (int k0 = 0; k0 < K; k0 += 16) {
        float4 ra = load4(A, (size_t)(bm + la_m) * K + k0 + la_k, a_bf);
        float4 rb = load4(B, (size_t)(k0 + lb_k) * N + bn + lb_n, b_bf);
        As[la_k + 0][la_m] = ra.x;
        As[la_k + 1][la_m] = ra.y;
        As[la_k + 2][la_m] = ra.z;
        As[la_k + 3][la_m] = ra.w;
        Bs[lb_k][lb_n + 0] = rb.x;
        Bs[lb_k][lb_n + 1] = rb.y;
        Bs[lb_k][lb_n + 2] = rb.z;
        Bs[lb_k][lb_n + 3] = rb.w;
        __syncthreads();
        #pragma unroll
        for (int kk = 0; kk < 16; ++kk) {
            float a0 = As[kk][ty * 4 + 0];
            float a1 = As[kk][ty * 4 + 1];
            float a2 = As[kk][ty * 4 + 2];
            float a3 = As[kk][ty * 4 + 3];
            float b0 = Bs[kk][tx * 4 + 0];
            float b1 = Bs[kk][tx * 4 + 1];
            float b2 = Bs[kk][tx * 4 + 2];
            float b3 = Bs[kk][tx * 4 + 3];
            acc[0][0] += a0 * b0; acc[0][1] += a0 * b1; acc[0][2] += a0 * b2; acc[0][3] += a0 * b3;
            acc[1][0] += a1 * b0; acc[1][1] += a1 * b1; acc[1][2] += a1 * b2; acc[1][3] += a1 * b3;
            acc[2][0] += a2 * b0; acc[2][1] += a2 * b1; acc[2][2] += a2 * b2; acc[2][3] += a2 * b3;
            acc[3][0] += a3 * b0; acc[3][1] += a3 * b1; acc[3][2] += a3 * b2; acc[3][3] += a3 * b3;
        }
        __syncthreads();
    }

    float bv[4];
    #pragma unroll
    for (int j = 0; j < 4; ++j) bv[j] = load1(bias, bn + tx * 4 + j, bias_bf);

    #pragma unroll
    for (int i = 0; i < 4; ++i) {
        const int row = bm + ty * 4 + i;
        const size_t off = (size_t)row * N + bn + tx * 4;
        float r0 = acc[i][0] + bv[0];
        float r1 = acc[i][1] + bv[1];
        float r2 = acc[i][2] + bv[2];
        float r3 = acc[i][3] + bv[3];
        if (c_bf) {
            alignas(8) unsigned short pk[4];
            pk[0] = f2us(r0); pk[1] = f2us(r1); pk[2] = f2us(r2); pk[3] = f2us(r3);
            *reinterpret_cast<ushort4*>((unsigned short*)C + off) =
                *reinterpret_cast<ushort4*>(pk);
        } else {
            *reinterpret_cast<float4*>((float*)C + off) = make_float4(r0, r1, r2, r3);
        }
    }
}

// Vt[bh][d][t] (bf16) from qkv bf16 [B*T, 3C] (V = cols [2C, 3C)).
__global__ __launch_bounds__(256) void transpose_v(
    const unsigned short* __restrict__ qkv, unsigned short* __restrict__ Vt)
{
    __shared__ __align__(16) unsigned short Ls[64 * 72];
    const int tid = threadIdx.x;
    const int tt = blockIdx.x;   // token tile
    const int bh = blockIdx.y;
    const int b = bh >> 4, h = bh & 15;
    {
        const int tok = tid & 63, w = tid >> 6;
        const unsigned short* src = qkv + (size_t)(b * TT + tt * 64 + tok) * 3 * CC + 2 * CC + h * HD;
        #pragma unroll
        for (int c2 = 0; c2 < 2; ++c2) {
            int c = 2 * w + c2;
            uint4 d = *(const uint4*)(src + c * 8);
            *(uint4*)(&Ls[tok * 72 + c * 8]) = d;
        }
    }
    __syncthreads();
    {
        const int d = tid >> 2, kq = tid & 3;
        unsigned short out[16];
        #pragma unroll
        for (int i = 0; i < 16; ++i) out[i] = Ls[(kq * 16 + i) * 72 + d];
        unsigned short* dst = Vt + (size_t)bh * HD * TT + (size_t)d * TT + tt * 64 + kq * 16;
        *(uint4*)(dst + 0) = *(uint4*)(&out[0]);
        *(uint4*)(dst + 8) = *(uint4*)(&out[8]);
    }
}

// MFMA flash attention. qkv bf16 [B*T,3C], Vt bf16 [BH][HD][TT], y f32 [B*T,C].
// Block = 256 threads (4 waves) = one 64-query tile of one (b,h).
// Wave w owns query rows w*16..w*16+15.
// Fragment-ordered LDS: slot(((nb*2+ks)*64 + q*16 + nn))*8+j holds element
// (n = nb*16+nn, k = ks*32+q*8+j); fragment read = b128 at slot(((nb*2+ks)*64+lane)*8).
__global__ __launch_bounds__(256) void attn_mfma(
    const unsigned short* __restrict__ qkv,
    const unsigned short* __restrict__ Vt,
    float* __restrict__ y)
{
    __shared__ __align__(16) unsigned short Ksh[64 * 64];
    __shared__ __align__(16) unsigned short Vsh[64 * 64];
    __shared__ __align__(16) unsigned short Psh[4][16 * 64];

    const int tid = threadIdx.x;
    const int l   = tid & 63;
    const int w   = tid >> 6;
    const int qt  = blockIdx.x;
    const int bh  = blockIdx.y;
    const int b   = bh >> 4, h = bh & 15;
    const int quad = l >> 4;
    const int col  = l & 15;

    // Q fragments (A-operand): m = lane&15, k = quad*8+j, two k-steps of 32.
    short8 qf[2];
    {
        const int token = qt * 64 + w * 16 + col;
        const unsigned short* qrow = qkv + (size_t)(b * TT + token) * 3 * CC + h * HD;
        qf[0] = *(const short8*)(qrow + quad * 8);
        qf[1] = *(const short8*)(qrow + 32 + quad * 8);
    }

    f32x4 o[4];
    #pragma unroll
    for (int nb = 0; nb < 4; ++nb) o[nb] = (f32x4){0.f, 0.f, 0.f, 0.f};
    float m_i[4] = {-3e38f, -3e38f, -3e38f, -3e38f};
    float l_i[4] = {0.f, 0.f, 0.f, 0.f};

    const unsigned short* kbase = qkv + (size_t)b * TT * 3 * CC + CC + h * HD;
    const unsigned short* vbase = Vt + (size_t)bh * HD * TT;

    const int s_nb = l >> 4, s_nn = l & 15;   // staging row split

    for (int kt = 0; kt <= qt; ++kt) {
        // ---- stage K (rows = keys) and V (rows = d, from Vt) fragment-ordered
        {
            const unsigned short* ksrc = kbase + (size_t)(kt * 64 + l) * 3 * CC;
            const unsigned short* vsrc = vbase + (size_t)l * TT + kt * 64;
            #pragma unroll
            for (int c2 = 0; c2 < 2; ++c2) {
                int c = 2 * w + c2;
                int ks = c >> 2, q = c & 3;
                int slot = ((s_nb * 2 + ks) * 64 + q * 16 + s_nn) * 8;
                uint4 dk = *(const uint4*)(ksrc + c * 8);
                *(uint4*)(&Ksh[slot]) = dk;
                uint4 dv = *(const uint4*)(vsrc + c * 8);
                *(uint4*)(&Vsh[slot]) = dv;
            }
        }
        __syncthreads();

        // ---- S = Q K^T  (wave slice 16x64)
        f32x4 s[4];
        #pragma unroll
        for (int nb = 0; nb < 4; ++nb) {
            f32x4 acc = {0.f, 0.f, 0.f, 0.f};
            #pragma unroll
            for (int ks = 0; ks < 2; ++ks) {
                short8 kf = *(const short8*)(&Ksh[((nb * 2 + ks) * 64 + l) * 8]);
                acc = __builtin_amdgcn_mfma_f32_16x16x32_bf16(qf[ks], kf, acc, 0, 0, 0);
            }
            s[nb] = acc;
        }

        // ---- online softmax (C-layout: col = lane&15 (+16nb), row = quad*4+reg)
        const bool diag = (kt == qt);
        float sv[4][4];
        #pragma unroll
        for (int nb = 0; nb < 4; ++nb) {
            #pragma unroll
            for (int r = 0; r < 4; ++r) {
                float v = s[nb][r] * 0.125f;
                if (diag) {
                    int kcol = nb * 16 + col;
                    int qr = w * 16 + quad * 4 + r;
                    if (kcol > qr) v = -3e38f;
                }
                sv[nb][r] = v;
            }
        }
        float mnew[4], alpha[4];
        #pragma unroll
        for (int r = 0; r < 4; ++r) {
            float rm = fmaxf(fmaxf(sv[0][r], sv[1][r]), fmaxf(sv[2][r], sv[3][r]));
            rm = fmaxf(rm, __shfl_xor(rm, 1));
            rm = fmaxf(rm, __shfl_xor(rm, 2));
            rm = fmaxf(rm, __shfl_xor(rm, 4));
            rm = fmaxf(rm, __shfl_xor(rm, 8));
            float mn = fmaxf(m_i[r], rm);
            mnew[r] = mn;
            alpha[r] = __expf(m_i[r] - mn);
        }
        // P = exp(S - m_new), scatter to A-frag layout in wave's LDS region
        float rsum[4] = {0.f, 0.f, 0.f, 0.f};
        #pragma unroll
        for (int nb = 0; nb < 4; ++nb) {
            const int ks = nb >> 1;
            const int q = ((nb & 1) << 1) | (col >> 3);
            const int j = col & 7;
            #pragma unroll
            for (int r = 0; r < 4; ++r) {
                float p = __expf(sv[nb][r] - mnew[r]);
                rsum[r] += p;
                Psh[w][(ks * 64 + q * 16 + (quad * 4 + r)) * 8 + j] = f2us(p);
            }
        }
        #pragma unroll
        for (int r = 0; r < 4; ++r) {
            float rs = rsum[r];
            rs += __shfl_xor(rs, 1);
            rs += __shfl_xor(rs, 2);
            rs += __shfl_xor(rs, 4);
            rs += __shfl_xor(rs, 8);
            l_i[r] = l_i[r] * alpha[r] + rs;
            m_i[r] = mnew[r];
        }
        #pragma unroll
        for (int nb = 0; nb < 4; ++nb)
            #pragma unroll
            for (int r = 0; r < 4; ++r)
                o[nb][r] *= alpha[r];

        // ---- O += P V
        short8 pf[2];
        pf[0] = *(const short8*)(&Psh[w][(0 * 64 + l) * 8]);
        pf[1] = *(const short8*)(&Psh[w][(1 * 64 + l) * 8]);
        #pragma unroll
        for (int nb = 0; nb < 4; ++nb) {
            #pragma unroll
            for (int ks = 0; ks < 2; ++ks) {
                short8 vf = *(const short8*)(&Vsh[((nb * 2 + ks) * 64 + l) * 8]);
                o[nb] = __builtin_amdgcn_mfma_f32_16x16x32_bf16(pf[ks], vf, o[nb], 0, 0, 0);
            }
        }
        __syncthreads();
    }

    // ---- epilogue: y (fp32)
    float inv[4];
    #pragma unroll
    for (int r = 0; r < 4; ++r) inv[r] = 1.f / l_i[r];
    #pragma unroll
    for (int nb = 0; nb < 4; ++nb) {
        #pragma unroll
        for (int r = 0; r < 4; ++r) {
            int token = qt * 64 + w * 16 + quad * 4 + r;
            y[(size_t)(b * TT + token) * CC + h * HD + nb * 16 + col] = o[nb][r] * inv[r];
        }
    }
}

extern "C" void kernel_launch(void* const* d_in, const int* in_sizes, int n_in,
                              void* d_out, int out_size, void* d_ws, size_t ws_size,
                              hipStream_t stream) {
    const int M = BB * TT;                      // 4096

    int*            flags = (int*)d_ws;
    unsigned short* qkv   = (unsigned short*)((char*)d_ws + 256);                 // [4096,3072] bf16
    unsigned short* Vt    = (unsigned short*)((char*)d_ws + 256
                              + (size_t)M * 3 * CC * sizeof(unsigned short));     // [32][64][2048] bf16
    float*          y     = (float*)((char*)d_ws + 256
                              + (size_t)M * 3 * CC * sizeof(unsigned short)
                              + (size_t)BB * NH * HD * TT * sizeof(unsigned short)); // [4096,1024] f32

    detect_kernel<<<1, 64, 0, stream>>>(d_in[0], d_in[1], d_in[2], d_in[3], d_in[4], flags);

    // 1) qkv = x @ W_qkv + b_qkv  -> bf16
    dim3 g1(3 * CC / 64, M / 64);
    gemm_bias<<<g1, 256, 0, stream>>>(d_in[0], d_in[1], d_in[2], qkv,
                                      M, 3 * CC, CC, flags, 0, 1, 2, -2);

    // 2) Vt = transpose(V)
    dim3 g2(TT / 64, BB * NH);
    transpose_v<<<g2, 256, 0, stream>>>(qkv, Vt);

    // 3) y = causal_attention(q, k, v)  (MFMA flash)
    dim3 g3(TT / 64, BB * NH);
    attn_mfma<<<g3, 256, 0, stream>>>(qkv, Vt, y);

    // 4) out = y @ W_o + b_o  (output dtype = x's dtype)
    dim3 g4(CC / 64, M / 64);
    gemm_bias<<<g4, 256, 0, stream>>>(y, d_in[3], d_in[4], d_out,
                                      M, CC, CC, flags, -1, 3, 4, 0);
}

// Round 4
// 351.546 us; speedup vs baseline: 7.1740x; 2.0651x over previous
//
#include <hip/hip_runtime.h>
#include <hip/hip_bf16.h>

#define TT 2048
#define BB 2
#define CC 1024
#define NH 16
#define HD 64

typedef __attribute__((ext_vector_type(8))) short short8;
typedef __attribute__((ext_vector_type(4))) float f32x4;

typedef unsigned int __attribute__((address_space(1))) ui_gas;
typedef unsigned int __attribute__((address_space(3))) ui_las;

__device__ __forceinline__ float us2f(unsigned short u) {
    union { unsigned int i; float f; } v; v.i = ((unsigned int)u) << 16; return v.f;
}
__device__ __forceinline__ unsigned short f2us(float f) {
    union { float f; unsigned int i; } v; v.f = f;
    unsigned int i = v.i;
    unsigned int lsb = (i >> 16) & 1u;
    i += 0x7fffu + lsb;           // round-to-nearest-even
    return (unsigned short)(i >> 16);
}

// async 16B/lane global->LDS: lds dest = wave-uniform base + lane*16
__device__ __forceinline__ void gl_lds16(const unsigned short* g, unsigned short* l) {
    __builtin_amdgcn_global_load_lds((const ui_gas*)g, (ui_las*)l, 16, 0, 0);
}

// One wave. Classify each input: bf16 data -> ~0 "huge/non-finite" lanes,
// fp32-read-as-bf16 -> ~45 of 64 lanes hit.
__global__ __launch_bounds__(64) void detect_kernel(
    const void* p0, const void* p1, const void* p2, const void* p3, const void* p4,
    int* flags)
{
    const void* ps[5] = {p0, p1, p2, p3, p4};
    const int lane = threadIdx.x;
    for (int k = 0; k < 5; ++k) {
        const unsigned short* u = (const unsigned short*)ps[k];
        int bad = 0;
        #pragma unroll
        for (int j = 0; j < 4; ++j) {
            float v = us2f(u[lane * 4 + j]);
            if (!(fabsf(v) < 1e4f)) bad = 1;
        }
        unsigned long long m = __ballot(bad != 0);
        if (lane == 0) flags[k] = (__popcll(m) < 4) ? 1 : 0;   // 1 = bf16
    }
}

__device__ __forceinline__ float4 load4(const void* p, size_t i, int isbf) {
    if (isbf) {
        ushort4 u = *reinterpret_cast<const ushort4*>((const unsigned short*)p + i);
        return make_float4(us2f(u.x), us2f(u.y), us2f(u.z), us2f(u.w));
    } else {
        return *reinterpret_cast<const float4*>((const float*)p + i);
    }
}
__device__ __forceinline__ float load1(const void* p, size_t i, int isbf) {
    return isbf ? us2f(((const unsigned short*)p)[i]) : ((const float*)p)[i];
}

// Elementwise X (fp32|bf16) -> Y bf16. 8 elems/thread.
__global__ __launch_bounds__(256) void convert_bf16(
    const void* __restrict__ X, unsigned short* __restrict__ Y,
    const int* __restrict__ flags, int fi)
{
    const int isbf = flags[fi];
    const size_t i = ((size_t)blockIdx.x * 256 + threadIdx.x) * 8;
    float4 a = load4(X, i, isbf);
    float4 b = load4(X, i + 4, isbf);
    alignas(16) unsigned short pk[8];
    pk[0] = f2us(a.x); pk[1] = f2us(a.y); pk[2] = f2us(a.z); pk[3] = f2us(a.w);
    pk[4] = f2us(b.x); pk[5] = f2us(b.y); pk[6] = f2us(b.z); pk[7] = f2us(b.w);
    *reinterpret_cast<uint4*>(Y + i) = *reinterpret_cast<const uint4*>(pk);
}

// Wt[N,K] bf16 = transpose(W[K,N] fp32|bf16). 64x64 tiles.
__global__ __launch_bounds__(256) void transpose_w(
    const void* __restrict__ W, unsigned short* __restrict__ Wt,
    int Krows, int N, const int* __restrict__ flags, int fi)
{
    const int isbf = flags[fi];
    __shared__ float Ls[64 * 65];
    const int t = threadIdx.x;
    const int n0 = blockIdx.x * 64, k0 = blockIdx.y * 64;
    {
        const int r = t >> 2, cq = (t & 3) << 4;
        #pragma unroll
        for (int i = 0; i < 4; ++i) {
            float4 v = load4(W, (size_t)(k0 + r) * N + n0 + cq + i * 4, isbf);
            Ls[r * 65 + cq + i * 4 + 0] = v.x;
            Ls[r * 65 + cq + i * 4 + 1] = v.y;
            Ls[r * 65 + cq + i * 4 + 2] = v.z;
            Ls[r * 65 + cq + i * 4 + 3] = v.w;
        }
    }
    __syncthreads();
    {
        const int c = t & 63, kg = (t >> 6) * 16;
        alignas(16) unsigned short pk[16];
        #pragma unroll
        for (int i = 0; i < 16; ++i) pk[i] = f2us(Ls[(kg + i) * 65 + c]);
        unsigned short* dst = Wt + (size_t)(n0 + c) * Krows + k0 + kg;
        *reinterpret_cast<uint4*>(dst + 0) = *reinterpret_cast<const uint4*>(&pk[0]);
        *reinterpret_cast<uint4*>(dst + 8) = *reinterpret_cast<const uint4*>(&pk[8]);
    }
}

// C[M,N] = A[M,K] * Bt[N,K]^T + bias[N]. bf16 MFMA, m97-style structure.
// 128x128 tile, BK=32, 256 threads (4 waves, 2x2), 4x4 16x16 tiles per wave.
// LDS fragment-ordered: slot r (16 rows) = 64 lanes x 16B, global_load_lds.
// cfi: >=0 -> flags[cfi] picks out dtype; -1 fp32; -2 bf16.
__global__ __launch_bounds__(256) void gemm_mfma(
    const unsigned short* __restrict__ A,   // [M,K] bf16
    const unsigned short* __restrict__ Bt,  // [N,K] bf16
    const void* __restrict__ bias, void* __restrict__ C,
    int M, int N, int K,
    const int* __restrict__ flags, int biasfi, int cfi)
{
    const int bias_bf = (biasfi >= 0) ? flags[biasfi] : 0;
    const int c_bf    = (cfi >= 0) ? flags[cfi] : ((cfi == -2) ? 1 : 0);

    __shared__ __align__(16) unsigned short Asl[8 * 512];  // 8 KB
    __shared__ __align__(16) unsigned short Bsl[8 * 512];  // 8 KB

    const int tid = threadIdx.x;
    const int l  = tid & 63;
    const int w  = tid >> 6;
    const int wm = w >> 1, wn = w & 1;
    const int bm = blockIdx.y * 128, bn = blockIdx.x * 128;
    const int lm = l & 15;
    const int lk = (l >> 4) * 8;

    f32x4 acc[4][4];
    #pragma unroll
    for (int i = 0; i < 4; ++i)
        #pragma unroll
        for (int j = 0; j < 4; ++j) acc[i][j] = (f32x4){0.f, 0.f, 0.f, 0.f};

    for (int k0 = 0; k0 < K; k0 += 32) {
        #pragma unroll
        for (int s = 0; s < 2; ++s) {
            const int r = 2 * w + s;
            gl_lds16(A  + (size_t)(bm + r * 16 + lm) * K + k0 + lk, &Asl[r * 512]);
            gl_lds16(Bt + (size_t)(bn + r * 16 + lm) * K + k0 + lk, &Bsl[r * 512]);
        }
        __syncthreads();
        short8 af[4], bf[4];
        #pragma unroll
        for (int i = 0; i < 4; ++i)
            af[i] = *reinterpret_cast<const short8*>(&Asl[(4 * wm + i) * 512 + l * 8]);
        #pragma unroll
        for (int j = 0; j < 4; ++j)
            bf[j] = *reinterpret_cast<const short8*>(&Bsl[(4 * wn + j) * 512 + l * 8]);
        #pragma unroll
        for (int i = 0; i < 4; ++i)
            #pragma unroll
            for (int j = 0; j < 4; ++j)
                acc[i][j] = __builtin_amdgcn_mfma_f32_16x16x32_bf16(af[i], bf[j], acc[i][j], 0, 0, 0);
        __syncthreads();
    }

    const int quad = l >> 4;
    float bv[4];
    #pragma unroll
    for (int j = 0; j < 4; ++j) bv[j] = load1(bias, bn + wn * 64 + j * 16 + lm, bias_bf);

    #pragma unroll
    for (int i = 0; i < 4; ++i) {
        #pragma unroll
        for (int r = 0; r < 4; ++r) {
            const int row = bm + wm * 64 + i * 16 + quad * 4 + r;
            #pragma unroll
            for (int j = 0; j < 4; ++j) {
                const int col = bn + wn * 64 + j * 16 + lm;
                const float val = acc[i][j][r] + bv[j];
                if (c_bf) ((unsigned short*)C)[(size_t)row * N + col] = f2us(val);
                else      ((float*)C)[(size_t)row * N + col] = val;
            }
        }
    }
}

// Vt[bh][d][t] (bf16) from qkv bf16 [B*T, 3C] (V = cols [2C, 3C)).
__global__ __launch_bounds__(256) void transpose_v(
    const unsigned short* __restrict__ qkv, unsigned short* __restrict__ Vt)
{
    __shared__ __align__(16) unsigned short Ls[64 * 72];
    const int tid = threadIdx.x;
    const int tt = blockIdx.x;
    const int bh = blockIdx.y;
    const int b = bh >> 4, h = bh & 15;
    {
        const int tok = tid & 63, w = tid >> 6;
        const unsigned short* src = qkv + (size_t)(b * TT + tt * 64 + tok) * 3 * CC + 2 * CC + h * HD;
        #pragma unroll
        for (int c2 = 0; c2 < 2; ++c2) {
            int c = 2 * w + c2;
            uint4 d = *(const uint4*)(src + c * 8);
            *(uint4*)(&Ls[tok * 72 + c * 8]) = d;
        }
    }
    __syncthreads();
    {
        const int d = tid >> 2, kq = tid & 3;
        unsigned short out[16];
        #pragma unroll
        for (int i = 0; i < 16; ++i) out[i] = Ls[(kq * 16 + i) * 72 + d];
        unsigned short* dst = Vt + (size_t)bh * HD * TT + (size_t)d * TT + tt * 64 + kq * 16;
        *(uint4*)(dst + 0) = *(uint4*)(&out[0]);
        *(uint4*)(dst + 8) = *(uint4*)(&out[8]);
    }
}

// MFMA flash attention. qkv bf16 [B*T,3C], Vt bf16 [BH][HD][TT], y bf16 [B*T,C].
// Block = 256 threads (4 waves) = one 64-query tile of one (b,h).
__global__ __launch_bounds__(256) void attn_mfma(
    const unsigned short* __restrict__ qkv,
    const unsigned short* __restrict__ Vt,
    unsigned short* __restrict__ y)
{
    __shared__ __align__(16) unsigned short Ksh[64 * 64];
    __shared__ __align__(16) unsigned short Vsh[64 * 64];
    __shared__ __align__(16) unsigned short Psh[4][16 * 64];

    const int tid = threadIdx.x;
    const int l   = tid & 63;
    const int w   = tid >> 6;
    const int qt  = blockIdx.x;
    const int bh  = blockIdx.y;
    const int b   = bh >> 4, h = bh & 15;
    const int quad = l >> 4;
    const int col  = l & 15;

    short8 qf[2];
    {
        const int token = qt * 64 + w * 16 + col;
        const unsigned short* qrow = qkv + (size_t)(b * TT + token) * 3 * CC + h * HD;
        qf[0] = *(const short8*)(qrow + quad * 8);
        qf[1] = *(const short8*)(qrow + 32 + quad * 8);
    }

    f32x4 o[4];
    #pragma unroll
    for (int nb = 0; nb < 4; ++nb) o[nb] = (f32x4){0.f, 0.f, 0.f, 0.f};
    float m_i[4] = {-3e38f, -3e38f, -3e38f, -3e38f};
    float l_i[4] = {0.f, 0.f, 0.f, 0.f};

    const unsigned short* kbase = qkv + (size_t)b * TT * 3 * CC + CC + h * HD;
    const unsigned short* vbase = Vt + (size_t)bh * HD * TT;

    const int s_nb = l >> 4, s_nn = l & 15;

    for (int kt = 0; kt <= qt; ++kt) {
        {
            const unsigned short* ksrc = kbase + (size_t)(kt * 64 + l) * 3 * CC;
            const unsigned short* vsrc = vbase + (size_t)l * TT + kt * 64;
            #pragma unroll
            for (int c2 = 0; c2 < 2; ++c2) {
                int c = 2 * w + c2;
                int ks = c >> 2, q = c & 3;
                int slot = ((s_nb * 2 + ks) * 64 + q * 16 + s_nn) * 8;
                uint4 dk = *(const uint4*)(ksrc + c * 8);
                *(uint4*)(&Ksh[slot]) = dk;
                uint4 dv = *(const uint4*)(vsrc + c * 8);
                *(uint4*)(&Vsh[slot]) = dv;
            }
        }
        __syncthreads();

        f32x4 s[4];
        #pragma unroll
        for (int nb = 0; nb < 4; ++nb) {
            f32x4 acc = {0.f, 0.f, 0.f, 0.f};
            #pragma unroll
            for (int ks = 0; ks < 2; ++ks) {
                short8 kf = *(const short8*)(&Ksh[((nb * 2 + ks) * 64 + l) * 8]);
                acc = __builtin_amdgcn_mfma_f32_16x16x32_bf16(qf[ks], kf, acc, 0, 0, 0);
            }
            s[nb] = acc;
        }

        const bool diag = (kt == qt);
        float sv[4][4];
        #pragma unroll
        for (int nb = 0; nb < 4; ++nb) {
            #pragma unroll
            for (int r = 0; r < 4; ++r) {
                float v = s[nb][r] * 0.125f;
                if (diag) {
                    int kcol = nb * 16 + col;
                    int qr = w * 16 + quad * 4 + r;
                    if (kcol > qr) v = -3e38f;
                }
                sv[nb][r] = v;
            }
        }
        float mnew[4], alpha[4];
        #pragma unroll
        for (int r = 0; r < 4; ++r) {
            float rm = fmaxf(fmaxf(sv[0][r], sv[1][r]), fmaxf(sv[2][r], sv[3][r]));
            rm = fmaxf(rm, __shfl_xor(rm, 1));
            rm = fmaxf(rm, __shfl_xor(rm, 2));
            rm = fmaxf(rm, __shfl_xor(rm, 4));
            rm = fmaxf(rm, __shfl_xor(rm, 8));
            float mn = fmaxf(m_i[r], rm);
            mnew[r] = mn;
            alpha[r] = __expf(m_i[r] - mn);
        }
        float rsum[4] = {0.f, 0.f, 0.f, 0.f};
        #pragma unroll
        for (int nb = 0; nb < 4; ++nb) {
            const int ks = nb >> 1;
            const int q = ((nb & 1) << 1) | (col >> 3);
            const int j = col & 7;
            #pragma unroll
            for (int r = 0; r < 4; ++r) {
                float p = __expf(sv[nb][r] - mnew[r]);
                rsum[r] += p;
                Psh[w][(ks * 64 + q * 16 + (quad * 4 + r)) * 8 + j] = f2us(p);
            }
        }
        #pragma unroll
        for (int r = 0; r < 4; ++r) {
            float rs = rsum[r];
            rs += __shfl_xor(rs, 1);
            rs += __shfl_xor(rs, 2);
            rs += __shfl_xor(rs, 4);
            rs += __shfl_xor(rs, 8);
            l_i[r] = l_i[r] * alpha[r] + rs;
            m_i[r] = mnew[r];
        }
        #pragma unroll
        for (int nb = 0; nb < 4; ++nb)
            #pragma unroll
            for (int r = 0; r < 4; ++r)
                o[nb][r] *= alpha[r];

        short8 pf[2];
        pf[0] = *(const short8*)(&Psh[w][(0 * 64 + l) * 8]);
        pf[1] = *(const short8*)(&Psh[w][(1 * 64 + l) * 8]);
        #pragma unroll
        for (int nb = 0; nb < 4; ++nb) {
            #pragma unroll
            for (int ks = 0; ks < 2; ++ks) {
                short8 vf = *(const short8*)(&Vsh[((nb * 2 + ks) * 64 + l) * 8]);
                o[nb] = __builtin_amdgcn_mfma_f32_16x16x32_bf16(pf[ks], vf, o[nb], 0, 0, 0);
            }
        }
        __syncthreads();
    }

    float inv[4];
    #pragma unroll
    for (int r = 0; r < 4; ++r) inv[r] = 1.f / l_i[r];
    #pragma unroll
    for (int nb = 0; nb < 4; ++nb) {
        #pragma unroll
        for (int r = 0; r < 4; ++r) {
            int token = qt * 64 + w * 16 + quad * 4 + r;
            y[(size_t)(b * TT + token) * CC + h * HD + nb * 16 + col] = f2us(o[nb][r] * inv[r]);
        }
    }
}

extern "C" void kernel_launch(void* const* d_in, const int* in_sizes, int n_in,
                              void* d_out, int out_size, void* d_ws, size_t ws_size,
                              hipStream_t stream) {
    const int M = BB * TT;                      // 4096

    char* ws = (char*)d_ws;
    int*            flags = (int*)ws;                         ws += 256;
    unsigned short* xb    = (unsigned short*)ws;              ws += (size_t)M * CC * 2;          // 8 MB
    unsigned short* Wqkvt = (unsigned short*)ws;              ws += (size_t)3 * CC * CC * 2;     // 6 MB
    unsigned short* Wot   = (unsigned short*)ws;              ws += (size_t)CC * CC * 2;         // 2 MB
    unsigned short* qkv   = (unsigned short*)ws;              ws += (size_t)M * 3 * CC * 2;      // 24 MB
    unsigned short* Vt    = (unsigned short*)ws;              ws += (size_t)BB * NH * HD * TT * 2; // 8 MB
    unsigned short* y     = (unsigned short*)ws;                                                  // 8 MB

    detect_kernel<<<1, 64, 0, stream>>>(d_in[0], d_in[1], d_in[2], d_in[3], d_in[4], flags);

    // 0) dtype conversion / weight transposes (one-time, ~15 us)
    convert_bf16<<<(M * CC) / (256 * 8), 256, 0, stream>>>(d_in[0], xb, flags, 0);
    transpose_w<<<dim3(3 * CC / 64, CC / 64), 256, 0, stream>>>(d_in[1], Wqkvt, CC, 3 * CC, flags, 1);
    transpose_w<<<dim3(CC / 64, CC / 64), 256, 0, stream>>>(d_in[3], Wot, CC, CC, flags, 3);

    // 1) qkv = x @ W_qkv + b_qkv  -> bf16   (MFMA)
    gemm_mfma<<<dim3(3 * CC / 128, M / 128), 256, 0, stream>>>(
        xb, Wqkvt, d_in[2], qkv, M, 3 * CC, CC, flags, 2, -2);

    // 2) Vt = transpose(V)
    transpose_v<<<dim3(TT / 64, BB * NH), 256, 0, stream>>>(qkv, Vt);

    // 3) y = causal_attention(q, k, v)  (MFMA flash) -> bf16
    attn_mfma<<<dim3(TT / 64, BB * NH), 256, 0, stream>>>(qkv, Vt, y);

    // 4) out = y @ W_o + b_o  (output dtype = x's dtype)   (MFMA)
    gemm_mfma<<<dim3(CC / 128, M / 128), 256, 0, stream>>>(
        y, Wot, d_in[4], d_out, M, CC, CC, flags, 4, 0);
}

// Round 5
// 287.149 us; speedup vs baseline: 8.7828x; 1.2243x over previous
//
#include <hip/hip_runtime.h>
#include <hip/hip_bf16.h>

#define TT 2048
#define BB 2
#define CC 1024
#define NH 16
#define HD 64

typedef __attribute__((ext_vector_type(8))) short short8;
typedef __attribute__((ext_vector_type(4))) float f32x4;

typedef unsigned int __attribute__((address_space(1))) ui_gas;
typedef unsigned int __attribute__((address_space(3))) ui_las;

__device__ __forceinline__ float us2f(unsigned short u) {
    union { unsigned int i; float f; } v; v.i = ((unsigned int)u) << 16; return v.f;
}
__device__ __forceinline__ unsigned short f2us(float f) {
    union { float f; unsigned int i; } v; v.f = f;
    unsigned int i = v.i;
    unsigned int lsb = (i >> 16) & 1u;
    i += 0x7fffu + lsb;           // round-to-nearest-even
    return (unsigned short)(i >> 16);
}

// async 16B/lane global->LDS: lds dest = wave-uniform base + lane*16
__device__ __forceinline__ void gl_lds16(const unsigned short* g, unsigned short* l) {
    __builtin_amdgcn_global_load_lds((const ui_gas*)g, (ui_las*)l, 16, 0, 0);
}

// One wave. Classify each input: bf16 data -> ~0 "huge/non-finite" lanes,
// fp32-read-as-bf16 -> ~45 of 64 lanes hit.
__global__ __launch_bounds__(64) void detect_kernel(
    const void* p0, const void* p1, const void* p2, const void* p3, const void* p4,
    int* flags)
{
    const void* ps[5] = {p0, p1, p2, p3, p4};
    const int lane = threadIdx.x;
    for (int k = 0; k < 5; ++k) {
        const unsigned short* u = (const unsigned short*)ps[k];
        int bad = 0;
        #pragma unroll
        for (int j = 0; j < 4; ++j) {
            float v = us2f(u[lane * 4 + j]);
            if (!(fabsf(v) < 1e4f)) bad = 1;
        }
        unsigned long long m = __ballot(bad != 0);
        if (lane == 0) flags[k] = (__popcll(m) < 4) ? 1 : 0;   // 1 = bf16
    }
}

__device__ __forceinline__ float4 load4(const void* p, size_t i, int isbf) {
    if (isbf) {
        ushort4 u = *reinterpret_cast<const ushort4*>((const unsigned short*)p + i);
        return make_float4(us2f(u.x), us2f(u.y), us2f(u.z), us2f(u.w));
    } else {
        return *reinterpret_cast<const float4*>((const float*)p + i);
    }
}
__device__ __forceinline__ float load1(const void* p, size_t i, int isbf) {
    return isbf ? us2f(((const unsigned short*)p)[i]) : ((const float*)p)[i];
}

// Elementwise X (fp32|bf16) -> Y bf16. 8 elems/thread.
__global__ __launch_bounds__(256) void convert_bf16(
    const void* __restrict__ X, unsigned short* __restrict__ Y,
    const int* __restrict__ flags, int fi)
{
    const int isbf = flags[fi];
    const size_t i = ((size_t)blockIdx.x * 256 + threadIdx.x) * 8;
    float4 a = load4(X, i, isbf);
    float4 b = load4(X, i + 4, isbf);
    alignas(16) unsigned short pk[8];
    pk[0] = f2us(a.x); pk[1] = f2us(a.y); pk[2] = f2us(a.z); pk[3] = f2us(a.w);
    pk[4] = f2us(b.x); pk[5] = f2us(b.y); pk[6] = f2us(b.z); pk[7] = f2us(b.w);
    *reinterpret_cast<uint4*>(Y + i) = *reinterpret_cast<const uint4*>(pk);
}

// Wt[N,K] bf16 = transpose(W[K,N] fp32|bf16). 64x64 tiles.
__global__ __launch_bounds__(256) void transpose_w(
    const void* __restrict__ W, unsigned short* __restrict__ Wt,
    int Krows, int N, const int* __restrict__ flags, int fi)
{
    const int isbf = flags[fi];
    __shared__ float Ls[64 * 65];
    const int t = threadIdx.x;
    const int n0 = blockIdx.x * 64, k0 = blockIdx.y * 64;
    {
        const int r = t >> 2, cq = (t & 3) << 4;
        #pragma unroll
        for (int i = 0; i < 4; ++i) {
            float4 v = load4(W, (size_t)(k0 + r) * N + n0 + cq + i * 4, isbf);
            Ls[r * 65 + cq + i * 4 + 0] = v.x;
            Ls[r * 65 + cq + i * 4 + 1] = v.y;
            Ls[r * 65 + cq + i * 4 + 2] = v.z;
            Ls[r * 65 + cq + i * 4 + 3] = v.w;
        }
    }
    __syncthreads();
    {
        const int c = t & 63, kg = (t >> 6) * 16;
        alignas(16) unsigned short pk[16];
        #pragma unroll
        for (int i = 0; i < 16; ++i) pk[i] = f2us(Ls[(kg + i) * 65 + c]);
        unsigned short* dst = Wt + (size_t)(n0 + c) * Krows + k0 + kg;
        *reinterpret_cast<uint4*>(dst + 0) = *reinterpret_cast<const uint4*>(&pk[0]);
        *reinterpret_cast<uint4*>(dst + 8) = *reinterpret_cast<const uint4*>(&pk[8]);
    }
}

// C[M,N] = A[M,K] * Bt[N,K]^T + bias[N]. bf16 MFMA, m97-style structure.
// 128x128 tile, BK=32, 256 threads (4 waves, 2x2), 4x4 16x16 tiles per wave.
__global__ __launch_bounds__(256) void gemm_mfma(
    const unsigned short* __restrict__ A,   // [M,K] bf16
    const unsigned short* __restrict__ Bt,  // [N,K] bf16
    const void* __restrict__ bias, void* __restrict__ C,
    int M, int N, int K,
    const int* __restrict__ flags, int biasfi, int cfi)
{
    const int bias_bf = (biasfi >= 0) ? flags[biasfi] : 0;
    const int c_bf    = (cfi >= 0) ? flags[cfi] : ((cfi == -2) ? 1 : 0);

    __shared__ __align__(16) unsigned short Asl[8 * 512];  // 8 KB
    __shared__ __align__(16) unsigned short Bsl[8 * 512];  // 8 KB

    const int tid = threadIdx.x;
    const int l  = tid & 63;
    const int w  = tid >> 6;
    const int wm = w >> 1, wn = w & 1;
    const int bm = blockIdx.y * 128, bn = blockIdx.x * 128;
    const int lm = l & 15;
    const int lk = (l >> 4) * 8;

    f32x4 acc[4][4];
    #pragma unroll
    for (int i = 0; i < 4; ++i)
        #pragma unroll
        for (int j = 0; j < 4; ++j) acc[i][j] = (f32x4){0.f, 0.f, 0.f, 0.f};

    for (int k0 = 0; k0 < K; k0 += 32) {
        #pragma unroll
        for (int s = 0; s < 2; ++s) {
            const int r = 2 * w + s;
            gl_lds16(A  + (size_t)(bm + r * 16 + lm) * K + k0 + lk, &Asl[r * 512]);
            gl_lds16(Bt + (size_t)(bn + r * 16 + lm) * K + k0 + lk, &Bsl[r * 512]);
        }
        __syncthreads();
        short8 af[4], bf[4];
        #pragma unroll
        for (int i = 0; i < 4; ++i)
            af[i] = *reinterpret_cast<const short8*>(&Asl[(4 * wm + i) * 512 + l * 8]);
        #pragma unroll
        for (int j = 0; j < 4; ++j)
            bf[j] = *reinterpret_cast<const short8*>(&Bsl[(4 * wn + j) * 512 + l * 8]);
        #pragma unroll
        for (int i = 0; i < 4; ++i)
            #pragma unroll
            for (int j = 0; j < 4; ++j)
                acc[i][j] = __builtin_amdgcn_mfma_f32_16x16x32_bf16(af[i], bf[j], acc[i][j], 0, 0, 0);
        __syncthreads();
    }

    const int quad = l >> 4;
    float bv[4];
    #pragma unroll
    for (int j = 0; j < 4; ++j) bv[j] = load1(bias, bn + wn * 64 + j * 16 + lm, bias_bf);

    #pragma unroll
    for (int i = 0; i < 4; ++i) {
        #pragma unroll
        for (int r = 0; r < 4; ++r) {
            const int row = bm + wm * 64 + i * 16 + quad * 4 + r;
            #pragma unroll
            for (int j = 0; j < 4; ++j) {
                const int col = bn + wn * 64 + j * 16 + lm;
                const float val = acc[i][j][r] + bv[j];
                if (c_bf) ((unsigned short*)C)[(size_t)row * N + col] = f2us(val);
                else      ((float*)C)[(size_t)row * N + col] = val;
            }
        }
    }
}

// Vt[bh][d][t] (bf16) from qkv bf16 [B*T, 3C] (V = cols [2C, 3C)).
__global__ __launch_bounds__(256) void transpose_v(
    const unsigned short* __restrict__ qkv, unsigned short* __restrict__ Vt)
{
    __shared__ __align__(16) unsigned short Ls[64 * 72];
    const int tid = threadIdx.x;
    const int tt = blockIdx.x;
    const int bh = blockIdx.y;
    const int b = bh >> 4, h = bh & 15;
    {
        const int tok = tid & 63, w = tid >> 6;
        const unsigned short* src = qkv + (size_t)(b * TT + tt * 64 + tok) * 3 * CC + 2 * CC + h * HD;
        #pragma unroll
        for (int c2 = 0; c2 < 2; ++c2) {
            int c = 2 * w + c2;
            uint4 d = *(const uint4*)(src + c * 8);
            *(uint4*)(&Ls[tok * 72 + c * 8]) = d;
        }
    }
    __syncthreads();
    {
        const int d = tid >> 2, kq = tid & 3;
        unsigned short out[16];
        #pragma unroll
        for (int i = 0; i < 16; ++i) out[i] = Ls[(kq * 16 + i) * 72 + d];
        unsigned short* dst = Vt + (size_t)bh * HD * TT + (size_t)d * TT + tt * 64 + kq * 16;
        *(uint4*)(dst + 0) = *(uint4*)(&out[0]);
        *(uint4*)(dst + 8) = *(uint4*)(&out[8]);
    }
}

// MFMA flash attention, balanced-pair version.
// Block n: XCD = n&7, g = n>>3; bh = (n&7)*4 + (g&3); i = g>>2.
// Handles q-tiles tA=i and tB=31-i (33 MFMA-steps/block, staging shared:
// tile A's kt range [0,i] is a subset of tile B's [0,31-i]).
// Reg-prefetch of next K/V tile overlaps global latency with compute.
__global__ __launch_bounds__(256) void attn_mfma(
    const unsigned short* __restrict__ qkv,
    const unsigned short* __restrict__ Vt,
    unsigned short* __restrict__ y)
{
    __shared__ __align__(16) unsigned short Ksh[64 * 64];
    __shared__ __align__(16) unsigned short Vsh[64 * 64];
    __shared__ __align__(16) unsigned short Psh[4][16 * 64];

    const int tid = threadIdx.x;
    const int l   = tid & 63;
    const int w   = tid >> 6;
    const int quad = l >> 4;
    const int col  = l & 15;

    const int n  = blockIdx.x;          // 0..511
    const int g  = n >> 3;
    const int bh = (n & 7) * 4 + (g & 3);
    const int i  = g >> 2;              // 0..15
    const int tA = i, tB = 31 - i;
    const int b  = bh >> 4, h = bh & 15;

    // Q fragments, 1/sqrt(64)=0.125 folded in (exact power-of-2 in bf16).
    short8 qfA[2], qfB[2];
    {
        #pragma unroll
        for (int t2 = 0; t2 < 2; ++t2) {
            const int qt = t2 ? tB : tA;
            short8* qf = t2 ? qfB : qfA;
            const int token = qt * 64 + w * 16 + col;
            const unsigned short* qrow = qkv + (size_t)(b * TT + token) * 3 * CC + h * HD;
            #pragma unroll
            for (int ks = 0; ks < 2; ++ks) {
                ushort4 u0 = *(const ushort4*)(qrow + ks * 32 + quad * 8);
                ushort4 u1 = *(const ushort4*)(qrow + ks * 32 + quad * 8 + 4);
                alignas(16) unsigned short pk[8];
                pk[0] = f2us(us2f(u0.x) * 0.125f);
                pk[1] = f2us(us2f(u0.y) * 0.125f);
                pk[2] = f2us(us2f(u0.z) * 0.125f);
                pk[3] = f2us(us2f(u0.w) * 0.125f);
                pk[4] = f2us(us2f(u1.x) * 0.125f);
                pk[5] = f2us(us2f(u1.y) * 0.125f);
                pk[6] = f2us(us2f(u1.z) * 0.125f);
                pk[7] = f2us(us2f(u1.w) * 0.125f);
                qf[ks] = *(const short8*)pk;
            }
        }
    }

    f32x4 oA[4], oB[4];
    float mA[4], lA[4], mB[4], lB[4];
    #pragma unroll
    for (int nb = 0; nb < 4; ++nb) {
        oA[nb] = (f32x4){0.f, 0.f, 0.f, 0.f};
        oB[nb] = (f32x4){0.f, 0.f, 0.f, 0.f};
    }
    #pragma unroll
    for (int r = 0; r < 4; ++r) { mA[r] = -3e38f; lA[r] = 0.f; mB[r] = -3e38f; lB[r] = 0.f; }

    const unsigned short* kbase = qkv + (size_t)b * TT * 3 * CC + CC + h * HD;
    const unsigned short* vbase = Vt + (size_t)bh * HD * TT;

    uint4 rk[2], rv[2];
    auto issue_loads = [&](int kt) {
        const unsigned short* ksrc = kbase + (size_t)(kt * 64 + l) * 3 * CC;
        const unsigned short* vsrc = vbase + (size_t)l * TT + kt * 64;
        #pragma unroll
        for (int c2 = 0; c2 < 2; ++c2) {
            const int c = 2 * w + c2;
            rk[c2] = *(const uint4*)(ksrc + c * 8);
            rv[c2] = *(const uint4*)(vsrc + c * 8);
        }
    };
    auto write_lds = [&]() {
        #pragma unroll
        for (int c2 = 0; c2 < 2; ++c2) {
            const int c = 2 * w + c2;
            const int ks = c >> 2, q = c & 3;
            const int slot = ((quad * 2 + ks) * 64 + q * 16 + col) * 8;
            *(uint4*)(&Ksh[slot]) = rk[c2];
            *(uint4*)(&Vsh[slot]) = rv[c2];
        }
    };

    auto step = [&](const short8* qf, f32x4* o, float* m_i, float* l_i, bool diag) {
        // ---- S = Q K^T  (16x64 per wave)
        f32x4 s[4];
        #pragma unroll
        for (int nb = 0; nb < 4; ++nb) {
            f32x4 acc = {0.f, 0.f, 0.f, 0.f};
            #pragma unroll
            for (int ks = 0; ks < 2; ++ks) {
                short8 kf = *(const short8*)(&Ksh[((nb * 2 + ks) * 64 + l) * 8]);
                acc = __builtin_amdgcn_mfma_f32_16x16x32_bf16(qf[ks], kf, acc, 0, 0, 0);
            }
            s[nb] = acc;
        }
        // ---- online softmax (C-layout: col=lane&15 (+16nb), row=quad*4+r)
        float sv[4][4];
        #pragma unroll
        for (int nb = 0; nb < 4; ++nb) {
            #pragma unroll
            for (int r = 0; r < 4; ++r) {
                float v = s[nb][r];
                if (diag) {
                    int kcol = nb * 16 + col;
                    int qr = w * 16 + quad * 4 + r;
                    if (kcol > qr) v = -3e38f;
                }
                sv[nb][r] = v;
            }
        }
        float mnew[4], alpha[4];
        #pragma unroll
        for (int r = 0; r < 4; ++r) {
            float rm = fmaxf(fmaxf(sv[0][r], sv[1][r]), fmaxf(sv[2][r], sv[3][r]));
            rm = fmaxf(rm, __shfl_xor(rm, 1));
            rm = fmaxf(rm, __shfl_xor(rm, 2));
            rm = fmaxf(rm, __shfl_xor(rm, 4));
            rm = fmaxf(rm, __shfl_xor(rm, 8));
            float mn = fmaxf(m_i[r], rm);
            mnew[r] = mn;
            alpha[r] = __expf(m_i[r] - mn);
        }
        float rsum[4] = {0.f, 0.f, 0.f, 0.f};
        #pragma unroll
        for (int nb = 0; nb < 4; ++nb) {
            const int ks = nb >> 1;
            const int q = ((nb & 1) << 1) | (col >> 3);
            const int j = col & 7;
            #pragma unroll
            for (int r = 0; r < 4; ++r) {
                float p = __expf(sv[nb][r] - mnew[r]);
                rsum[r] += p;
                Psh[w][(ks * 64 + q * 16 + (quad * 4 + r)) * 8 + j] = f2us(p);
            }
        }
        #pragma unroll
        for (int r = 0; r < 4; ++r) {
            float rs = rsum[r];
            rs += __shfl_xor(rs, 1);
            rs += __shfl_xor(rs, 2);
            rs += __shfl_xor(rs, 4);
            rs += __shfl_xor(rs, 8);
            l_i[r] = l_i[r] * alpha[r] + rs;
            m_i[r] = mnew[r];
        }
        #pragma unroll
        for (int nb = 0; nb < 4; ++nb)
            #pragma unroll
            for (int r = 0; r < 4; ++r)
                o[nb][r] *= alpha[r];
        // ---- O += P V
        short8 pf[2];
        pf[0] = *(const short8*)(&Psh[w][(0 * 64 + l) * 8]);
        pf[1] = *(const short8*)(&Psh[w][(1 * 64 + l) * 8]);
        #pragma unroll
        for (int nb = 0; nb < 4; ++nb) {
            #pragma unroll
            for (int ks = 0; ks < 2; ++ks) {
                short8 vf = *(const short8*)(&Vsh[((nb * 2 + ks) * 64 + l) * 8]);
                o[nb] = __builtin_amdgcn_mfma_f32_16x16x32_bf16(pf[ks], vf, o[nb], 0, 0, 0);
            }
        }
    };

    issue_loads(0);
    for (int kt = 0; kt <= tB; ++kt) {
        write_lds();
        __syncthreads();
        if (kt < tB) issue_loads(kt + 1);       // prefetch overlaps compute
        step(qfB, oB, mB, lB, kt == tB);
        if (kt <= tA) step(qfA, oA, mA, lA, kt == tA);
        __syncthreads();
    }

    // ---- epilogue
    #pragma unroll
    for (int t2 = 0; t2 < 2; ++t2) {
        const int qt = t2 ? tB : tA;
        f32x4* o = t2 ? oB : oA;
        float* l_i = t2 ? lB : lA;
        float inv[4];
        #pragma unroll
        for (int r = 0; r < 4; ++r) inv[r] = 1.f / l_i[r];
        #pragma unroll
        for (int nb = 0; nb < 4; ++nb) {
            #pragma unroll
            for (int r = 0; r < 4; ++r) {
                int token = qt * 64 + w * 16 + quad * 4 + r;
                y[(size_t)(b * TT + token) * CC + h * HD + nb * 16 + col] = f2us(o[nb][r] * inv[r]);
            }
        }
    }
}

extern "C" void kernel_launch(void* const* d_in, const int* in_sizes, int n_in,
                              void* d_out, int out_size, void* d_ws, size_t ws_size,
                              hipStream_t stream) {
    const int M = BB * TT;                      // 4096

    char* ws = (char*)d_ws;
    int*            flags = (int*)ws;                         ws += 256;
    unsigned short* xb    = (unsigned short*)ws;              ws += (size_t)M * CC * 2;          // 8 MB
    unsigned short* Wqkvt = (unsigned short*)ws;              ws += (size_t)3 * CC * CC * 2;     // 6 MB
    unsigned short* Wot   = (unsigned short*)ws;              ws += (size_t)CC * CC * 2;         // 2 MB
    unsigned short* qkv   = (unsigned short*)ws;              ws += (size_t)M * 3 * CC * 2;      // 24 MB
    unsigned short* Vt    = (unsigned short*)ws;              ws += (size_t)BB * NH * HD * TT * 2; // 8 MB
    unsigned short* y     = (unsigned short*)ws;                                                  // 8 MB

    detect_kernel<<<1, 64, 0, stream>>>(d_in[0], d_in[1], d_in[2], d_in[3], d_in[4], flags);

    // 0) dtype conversion / weight transposes
    convert_bf16<<<(M * CC) / (256 * 8), 256, 0, stream>>>(d_in[0], xb, flags, 0);
    transpose_w<<<dim3(3 * CC / 64, CC / 64), 256, 0, stream>>>(d_in[1], Wqkvt, CC, 3 * CC, flags, 1);
    transpose_w<<<dim3(CC / 64, CC / 64), 256, 0, stream>>>(d_in[3], Wot, CC, CC, flags, 3);

    // 1) qkv = x @ W_qkv + b_qkv  -> bf16   (MFMA)
    gemm_mfma<<<dim3(3 * CC / 128, M / 128), 256, 0, stream>>>(
        xb, Wqkvt, d_in[2], qkv, M, 3 * CC, CC, flags, 2, -2);

    // 2) Vt = transpose(V)
    transpose_v<<<dim3(TT / 64, BB * NH), 256, 0, stream>>>(qkv, Vt);

    // 3) y = causal_attention(q, k, v)  (balanced-pair MFMA flash) -> bf16
    attn_mfma<<<512, 256, 0, stream>>>(qkv, Vt, y);

    // 4) out = y @ W_o + b_o  (output dtype = x's dtype)   (MFMA)
    gemm_mfma<<<dim3(CC / 128, M / 128), 256, 0, stream>>>(
        y, Wot, d_in[4], d_out, M, CC, CC, flags, 4, 0);
}

// Round 6
// 248.539 us; speedup vs baseline: 10.1472x; 1.1553x over previous
//
#include <hip/hip_runtime.h>
#include <hip/hip_bf16.h>

#define TT 2048
#define BB 2
#define CC 1024
#define NH 16
#define HD 64

typedef __attribute__((ext_vector_type(8))) short short8;
typedef __attribute__((ext_vector_type(4))) short short4b;
typedef __attribute__((ext_vector_type(4))) float f32x4;

typedef unsigned int __attribute__((address_space(1))) ui_gas;
typedef unsigned int __attribute__((address_space(3))) ui_las;

__device__ __forceinline__ float us2f(unsigned short u) {
    union { unsigned int i; float f; } v; v.i = ((unsigned int)u) << 16; return v.f;
}
__device__ __forceinline__ unsigned short f2us(float f) {
    union { float f; unsigned int i; } v; v.f = f;
    unsigned int i = v.i;
    unsigned int lsb = (i >> 16) & 1u;
    i += 0x7fffu + lsb;           // round-to-nearest-even
    return (unsigned short)(i >> 16);
}
// pack two fp32 -> bf16x2 dword by truncation (for P in [0,1]; <=1ulp bias)
__device__ __forceinline__ unsigned int pack2_trunc(float a, float b) {
    union { float f; unsigned int u; } x, y; x.f = a; y.f = b;
    return (y.u & 0xffff0000u) | (x.u >> 16);
}

// async 16B/lane global->LDS: lds dest = wave-uniform base + lane*16
__device__ __forceinline__ void gl_lds16(const unsigned short* g, unsigned short* l) {
    __builtin_amdgcn_global_load_lds((const ui_gas*)g, (ui_las*)l, 16, 0, 0);
}

// One wave. Classify each input: bf16 data -> ~0 "huge/non-finite" lanes,
// fp32-read-as-bf16 -> ~45 of 64 lanes hit.
__global__ __launch_bounds__(64) void detect_kernel(
    const void* p0, const void* p1, const void* p2, const void* p3, const void* p4,
    int* flags)
{
    const void* ps[5] = {p0, p1, p2, p3, p4};
    const int lane = threadIdx.x;
    for (int k = 0; k < 5; ++k) {
        const unsigned short* u = (const unsigned short*)ps[k];
        int bad = 0;
        #pragma unroll
        for (int j = 0; j < 4; ++j) {
            float v = us2f(u[lane * 4 + j]);
            if (!(fabsf(v) < 1e4f)) bad = 1;
        }
        unsigned long long m = __ballot(bad != 0);
        if (lane == 0) flags[k] = (__popcll(m) < 4) ? 1 : 0;   // 1 = bf16
    }
}

__device__ __forceinline__ float4 load4(const void* p, size_t i, int isbf) {
    if (isbf) {
        ushort4 u = *reinterpret_cast<const ushort4*>((const unsigned short*)p + i);
        return make_float4(us2f(u.x), us2f(u.y), us2f(u.z), us2f(u.w));
    } else {
        return *reinterpret_cast<const float4*>((const float*)p + i);
    }
}
__device__ __forceinline__ float load1(const void* p, size_t i, int isbf) {
    return isbf ? us2f(((const unsigned short*)p)[i]) : ((const float*)p)[i];
}

// Elementwise X (fp32|bf16) -> Y bf16. 8 elems/thread.
__global__ __launch_bounds__(256) void convert_bf16(
    const void* __restrict__ X, unsigned short* __restrict__ Y,
    const int* __restrict__ flags, int fi)
{
    const int isbf = flags[fi];
    const size_t i = ((size_t)blockIdx.x * 256 + threadIdx.x) * 8;
    float4 a = load4(X, i, isbf);
    float4 b = load4(X, i + 4, isbf);
    alignas(16) unsigned short pk[8];
    pk[0] = f2us(a.x); pk[1] = f2us(a.y); pk[2] = f2us(a.z); pk[3] = f2us(a.w);
    pk[4] = f2us(b.x); pk[5] = f2us(b.y); pk[6] = f2us(b.z); pk[7] = f2us(b.w);
    *reinterpret_cast<uint4*>(Y + i) = *reinterpret_cast<const uint4*>(pk);
}

// Wt[N,K] bf16 = transpose(W[K,N] fp32|bf16). 64x64 tiles.
__global__ __launch_bounds__(256) void transpose_w(
    const void* __restrict__ W, unsigned short* __restrict__ Wt,
    int Krows, int N, const int* __restrict__ flags, int fi)
{
    const int isbf = flags[fi];
    __shared__ float Ls[64 * 65];
    const int t = threadIdx.x;
    const int n0 = blockIdx.x * 64, k0 = blockIdx.y * 64;
    {
        const int r = t >> 2, cq = (t & 3) << 4;
        #pragma unroll
        for (int i = 0; i < 4; ++i) {
            float4 v = load4(W, (size_t)(k0 + r) * N + n0 + cq + i * 4, isbf);
            Ls[r * 65 + cq + i * 4 + 0] = v.x;
            Ls[r * 65 + cq + i * 4 + 1] = v.y;
            Ls[r * 65 + cq + i * 4 + 2] = v.z;
            Ls[r * 65 + cq + i * 4 + 3] = v.w;
        }
    }
    __syncthreads();
    {
        const int c = t & 63, kg = (t >> 6) * 16;
        alignas(16) unsigned short pk[16];
        #pragma unroll
        for (int i = 0; i < 16; ++i) pk[i] = f2us(Ls[(kg + i) * 65 + c]);
        unsigned short* dst = Wt + (size_t)(n0 + c) * Krows + k0 + kg;
        *reinterpret_cast<uint4*>(dst + 0) = *reinterpret_cast<const uint4*>(&pk[0]);
        *reinterpret_cast<uint4*>(dst + 8) = *reinterpret_cast<const uint4*>(&pk[8]);
    }
}

// C[M,N] = A[M,K] * Bt[N,K]^T + bias[N]. bf16 MFMA, m97-style structure.
__global__ __launch_bounds__(256) void gemm_mfma(
    const unsigned short* __restrict__ A,   // [M,K] bf16
    const unsigned short* __restrict__ Bt,  // [N,K] bf16
    const void* __restrict__ bias, void* __restrict__ C,
    int M, int N, int K,
    const int* __restrict__ flags, int biasfi, int cfi)
{
    const int bias_bf = (biasfi >= 0) ? flags[biasfi] : 0;
    const int c_bf    = (cfi >= 0) ? flags[cfi] : ((cfi == -2) ? 1 : 0);

    __shared__ __align__(16) unsigned short Asl[8 * 512];
    __shared__ __align__(16) unsigned short Bsl[8 * 512];

    const int tid = threadIdx.x;
    const int l  = tid & 63;
    const int w  = tid >> 6;
    const int wm = w >> 1, wn = w & 1;
    const int bm = blockIdx.y * 128, bn = blockIdx.x * 128;
    const int lm = l & 15;
    const int lk = (l >> 4) * 8;

    f32x4 acc[4][4];
    #pragma unroll
    for (int i = 0; i < 4; ++i)
        #pragma unroll
        for (int j = 0; j < 4; ++j) acc[i][j] = (f32x4){0.f, 0.f, 0.f, 0.f};

    for (int k0 = 0; k0 < K; k0 += 32) {
        #pragma unroll
        for (int s = 0; s < 2; ++s) {
            const int r = 2 * w + s;
            gl_lds16(A  + (size_t)(bm + r * 16 + lm) * K + k0 + lk, &Asl[r * 512]);
            gl_lds16(Bt + (size_t)(bn + r * 16 + lm) * K + k0 + lk, &Bsl[r * 512]);
        }
        __syncthreads();
        short8 af[4], bf[4];
        #pragma unroll
        for (int i = 0; i < 4; ++i)
            af[i] = *reinterpret_cast<const short8*>(&Asl[(4 * wm + i) * 512 + l * 8]);
        #pragma unroll
        for (int j = 0; j < 4; ++j)
            bf[j] = *reinterpret_cast<const short8*>(&Bsl[(4 * wn + j) * 512 + l * 8]);
        #pragma unroll
        for (int i = 0; i < 4; ++i)
            #pragma unroll
            for (int j = 0; j < 4; ++j)
                acc[i][j] = __builtin_amdgcn_mfma_f32_16x16x32_bf16(af[i], bf[j], acc[i][j], 0, 0, 0);
        __syncthreads();
    }

    const int quad = l >> 4;
    float bv[4];
    #pragma unroll
    for (int j = 0; j < 4; ++j) bv[j] = load1(bias, bn + wn * 64 + j * 16 + lm, bias_bf);

    #pragma unroll
    for (int i = 0; i < 4; ++i) {
        #pragma unroll
        for (int r = 0; r < 4; ++r) {
            const int row = bm + wm * 64 + i * 16 + quad * 4 + r;
            #pragma unroll
            for (int j = 0; j < 4; ++j) {
                const int col = bn + wn * 64 + j * 16 + lm;
                const float val = acc[i][j][r] + bv[j];
                if (c_bf) ((unsigned short*)C)[(size_t)row * N + col] = f2us(val);
                else      ((float*)C)[(size_t)row * N + col] = val;
            }
        }
    }
}

// Vt[bh][d][t] (bf16) from qkv bf16 [B*T, 3C] (V = cols [2C, 3C)).
__global__ __launch_bounds__(256) void transpose_v(
    const unsigned short* __restrict__ qkv, unsigned short* __restrict__ Vt)
{
    __shared__ __align__(16) unsigned short Ls[64 * 72];
    const int tid = threadIdx.x;
    const int tt = blockIdx.x;
    const int bh = blockIdx.y;
    const int b = bh >> 4, h = bh & 15;
    {
        const int tok = tid & 63, w = tid >> 6;
        const unsigned short* src = qkv + (size_t)(b * TT + tt * 64 + tok) * 3 * CC + 2 * CC + h * HD;
        #pragma unroll
        for (int c2 = 0; c2 < 2; ++c2) {
            int c = 2 * w + c2;
            uint4 d = *(const uint4*)(src + c * 8);
            *(uint4*)(&Ls[tok * 72 + c * 8]) = d;
        }
    }
    __syncthreads();
    {
        const int d = tid >> 2, kq = tid & 3;
        unsigned short out[16];
        #pragma unroll
        for (int i = 0; i < 16; ++i) out[i] = Ls[(kq * 16 + i) * 72 + d];
        unsigned short* dst = Vt + (size_t)bh * HD * TT + (size_t)d * TT + tt * 64 + kq * 16;
        *(uint4*)(dst + 0) = *(uint4*)(&out[0]);
        *(uint4*)(dst + 8) = *(uint4*)(&out[8]);
    }
}

// MFMA flash attention, S^T formulation (P born in A-operand layout).
// Block n: XCD = n&7; bh = (n&7)*4 + ((n>>3)&3); i = n>>5; q-tiles tA=i, tB=31-i.
// Wave w owns queries w*16+col (col = lane&15); per-lane softmax state.
// Ksh fragment-ordered (A-operand K tiles); Vsh = V^T in 16B slots
// (g=keygroup, d) at slot g*65+d, lower 4 halfwords = keys g*4..g*4+3,
// upper 4 pre-zeroed (enables zero-padded K=32 PV fallback).
__global__ __launch_bounds__(256) void attn_mfma(
    const unsigned short* __restrict__ qkv,
    const unsigned short* __restrict__ Vt,
    unsigned short* __restrict__ y)
{
    __shared__ __align__(16) unsigned short Ksh[8 * 512];     // 8 KB
    __shared__ __align__(16) unsigned short Vsh[1039 * 8];    // ~16.6 KB

    const int tid = threadIdx.x;
    const int l   = tid & 63;
    const int w   = tid >> 6;
    const int quad = l >> 4;
    const int col  = l & 15;

    const int n  = blockIdx.x;          // 0..511
    const int g  = n >> 3;
    const int bh = (n & 7) * 4 + (g & 3);
    const int i  = g >> 2;              // 0..15
    const int tA = i, tB = 31 - i;
    const int b  = bh >> 4, h = bh & 15;

    // zero the upper half of every Vsh slot once (PV zero-pad / unused lanes)
    for (int s = tid; s < 1039; s += 256)
        *(uint2*)(&Vsh[s * 8 + 4]) = make_uint2(0u, 0u);

    // Q fragments (B-operand: n=col, k=quad*8+j), scale 0.125*log2(e) folded.
    const float QSCALE = 0.18033688f;
    short8 qfA[2], qfB[2];
    #pragma unroll
    for (int t2 = 0; t2 < 2; ++t2) {
        const int qt = t2 ? tB : tA;
        short8* qf = t2 ? qfB : qfA;
        const int token = qt * 64 + w * 16 + col;
        const unsigned short* qrow = qkv + (size_t)(b * TT + token) * 3 * CC + h * HD;
        #pragma unroll
        for (int ks = 0; ks < 2; ++ks) {
            ushort4 u0 = *(const ushort4*)(qrow + ks * 32 + quad * 8);
            ushort4 u1 = *(const ushort4*)(qrow + ks * 32 + quad * 8 + 4);
            alignas(16) unsigned short pk[8];
            pk[0] = f2us(us2f(u0.x) * QSCALE);
            pk[1] = f2us(us2f(u0.y) * QSCALE);
            pk[2] = f2us(us2f(u0.z) * QSCALE);
            pk[3] = f2us(us2f(u0.w) * QSCALE);
            pk[4] = f2us(us2f(u1.x) * QSCALE);
            pk[5] = f2us(us2f(u1.y) * QSCALE);
            pk[6] = f2us(us2f(u1.z) * QSCALE);
            pk[7] = f2us(us2f(u1.w) * QSCALE);
            qf[ks] = *(const short8*)pk;
        }
    }

    f32x4 oA[4], oB[4];
    #pragma unroll
    for (int nb = 0; nb < 4; ++nb) {
        oA[nb] = (f32x4){0.f, 0.f, 0.f, 0.f};
        oB[nb] = (f32x4){0.f, 0.f, 0.f, 0.f};
    }
    float mA = -3e38f, lAc = 0.f, mB = -3e38f, lBc = 0.f;

    const unsigned short* kbase = qkv + (size_t)b * TT * 3 * CC + CC + h * HD;
    const unsigned short* vbase = Vt + (size_t)bh * HD * TT;

    const int vd = tid >> 2, vg0 = (tid & 3) * 4;

    uint4 rk[2], rv[2];
    auto issue_loads = [&](int kt) {
        const unsigned short* ksrc = kbase + (size_t)(kt * 64 + l) * 3 * CC;
        #pragma unroll
        for (int c2 = 0; c2 < 2; ++c2) {
            const int c = 2 * w + c2;
            rk[c2] = *(const uint4*)(ksrc + c * 8);
        }
        const unsigned short* vsrc = vbase + (size_t)vd * TT + kt * 64 + vg0 * 4;
        rv[0] = *(const uint4*)(vsrc + 0);
        rv[1] = *(const uint4*)(vsrc + 8);
    };
    auto write_lds = [&]() {
        #pragma unroll
        for (int c2 = 0; c2 < 2; ++c2) {
            const int c = 2 * w + c2;
            const int ks = c >> 2, q = c & 3;
            const int slot = ((quad * 2 + ks) * 64 + q * 16 + col) * 8;
            *(uint4*)(&Ksh[slot]) = rk[c2];
        }
        *(uint2*)(&Vsh[((vg0 + 0) * 65 + vd) * 8]) = make_uint2(rv[0].x, rv[0].y);
        *(uint2*)(&Vsh[((vg0 + 1) * 65 + vd) * 8]) = make_uint2(rv[0].z, rv[0].w);
        *(uint2*)(&Vsh[((vg0 + 2) * 65 + vd) * 8]) = make_uint2(rv[1].x, rv[1].y);
        *(uint2*)(&Vsh[((vg0 + 3) * 65 + vd) * 8]) = make_uint2(rv[1].z, rv[1].w);
    };

    auto step = [&](const short8* qf, f32x4* o, float& m_i, float& l_i, bool diag) {
        // ---- S^T = K Q^T : tile nb covers keys nb*16..+15 (rows), queries (cols)
        f32x4 st[4];
        #pragma unroll
        for (int nb = 0; nb < 4; ++nb) {
            f32x4 acc = {0.f, 0.f, 0.f, 0.f};
            #pragma unroll
            for (int ks = 0; ks < 2; ++ks) {
                short8 kf = *(const short8*)(&Ksh[((nb * 2 + ks) * 64 + l) * 8]);
                acc = __builtin_amdgcn_mfma_f32_16x16x32_bf16(kf, qf[ks], acc, 0, 0, 0);
            }
            st[nb] = acc;
        }
        // lane holds S[query=col][key=nb*16+quad*4+r], log2 domain
        float sv[4][4];
        #pragma unroll
        for (int nb = 0; nb < 4; ++nb)
            #pragma unroll
            for (int r = 0; r < 4; ++r) {
                float v = st[nb][r];
                if (diag && (nb * 16 + quad * 4 + r > w * 16 + col)) v = -3e38f;
                sv[nb][r] = v;
            }
        // per-query (per-lane) max over 16 regs + cross-quad
        float rm = sv[0][0];
        #pragma unroll
        for (int nb = 0; nb < 4; ++nb)
            #pragma unroll
            for (int r = 0; r < 4; ++r) rm = fmaxf(rm, sv[nb][r]);
        rm = fmaxf(rm, __shfl_xor(rm, 16));
        rm = fmaxf(rm, __shfl_xor(rm, 32));
        const float mn = fmaxf(m_i, rm);
        const float al = __builtin_exp2f(m_i - mn);
        float pv[4][4];
        float rs = 0.f;
        #pragma unroll
        for (int nb = 0; nb < 4; ++nb)
            #pragma unroll
            for (int r = 0; r < 4; ++r) {
                float p = __builtin_exp2f(sv[nb][r] - mn);
                pv[nb][r] = p;
                rs += p;
            }
        rs += __shfl_xor(rs, 16);
        rs += __shfl_xor(rs, 32);
        l_i = l_i * al + rs;
        m_i = mn;
        // rescale O (rows are queries quad*4+r -> fetch alpha from lane quad*4+r)
        float alr[4];
        #pragma unroll
        for (int r = 0; r < 4; ++r) alr[r] = __shfl(al, quad * 4 + r);
        #pragma unroll
        for (int nb = 0; nb < 4; ++nb)
            #pragma unroll
            for (int r = 0; r < 4; ++r) o[nb][r] *= alr[r];
        // ---- O += P V  (P already in A-layout)
#if __has_builtin(__builtin_amdgcn_mfma_f32_16x16x16bf16_1k)
        short4b pf[4];
        #pragma unroll
        for (int nbk = 0; nbk < 4; ++nbk) {
            union { short4b s; unsigned int u[2]; } pk;
            pk.u[0] = pack2_trunc(pv[nbk][0], pv[nbk][1]);
            pk.u[1] = pack2_trunc(pv[nbk][2], pv[nbk][3]);
            pf[nbk] = pk.s;
        }
        #pragma unroll
        for (int nbd = 0; nbd < 4; ++nbd)
            #pragma unroll
            for (int nbk = 0; nbk < 4; ++nbk) {
                short4b vf = *(const short4b*)(&Vsh[((nbk * 4 + quad) * 65 + nbd * 16 + col) * 8]);
                o[nbd] = __builtin_amdgcn_mfma_f32_16x16x16bf16_1k(pf[nbk], vf, o[nbd], 0, 0, 0);
            }
#else
        short8 pf[4];
        #pragma unroll
        for (int nbk = 0; nbk < 4; ++nbk) {
            union { short8 s; unsigned int u[4]; } pk;
            pk.u[0] = pack2_trunc(pv[nbk][0], pv[nbk][1]);
            pk.u[1] = pack2_trunc(pv[nbk][2], pv[nbk][3]);
            pk.u[2] = 0u; pk.u[3] = 0u;
            pf[nbk] = pk.s;
        }
        #pragma unroll
        for (int nbd = 0; nbd < 4; ++nbd)
            #pragma unroll
            for (int nbk = 0; nbk < 4; ++nbk) {
                short8 vf = *(const short8*)(&Vsh[((nbk * 4 + quad) * 65 + nbd * 16 + col) * 8]);
                o[nbd] = __builtin_amdgcn_mfma_f32_16x16x32_bf16(pf[nbk], vf, o[nbd], 0, 0, 0);
            }
#endif
    };

    issue_loads(0);
    for (int kt = 0; kt <= tB; ++kt) {
        write_lds();
        __syncthreads();
        if (kt < tB) issue_loads(kt + 1);       // prefetch overlaps compute
        step(qfB, oB, mB, lBc, kt == tB);
        if (kt <= tA) step(qfA, oA, mA, lAc, kt == tA);
        __syncthreads();
    }

    // ---- epilogue: O rows are queries quad*4+r; 1/l fetched from lane quad*4+r
    #pragma unroll
    for (int t2 = 0; t2 < 2; ++t2) {
        const int qt = t2 ? tB : tA;
        f32x4* o = t2 ? oB : oA;
        const float inv = 1.f / (t2 ? lBc : lAc);
        float invr[4];
        #pragma unroll
        for (int r = 0; r < 4; ++r) invr[r] = __shfl(inv, quad * 4 + r);
        #pragma unroll
        for (int nb = 0; nb < 4; ++nb)
            #pragma unroll
            for (int r = 0; r < 4; ++r) {
                int token = qt * 64 + w * 16 + quad * 4 + r;
                y[(size_t)(b * TT + token) * CC + h * HD + nb * 16 + col] = f2us(o[nb][r] * invr[r]);
            }
    }
}

extern "C" void kernel_launch(void* const* d_in, const int* in_sizes, int n_in,
                              void* d_out, int out_size, void* d_ws, size_t ws_size,
                              hipStream_t stream) {
    const int M = BB * TT;                      // 4096

    char* ws = (char*)d_ws;
    int*            flags = (int*)ws;                         ws += 256;
    unsigned short* xb    = (unsigned short*)ws;              ws += (size_t)M * CC * 2;
    unsigned short* Wqkvt = (unsigned short*)ws;              ws += (size_t)3 * CC * CC * 2;
    unsigned short* Wot   = (unsigned short*)ws;              ws += (size_t)CC * CC * 2;
    unsigned short* qkv   = (unsigned short*)ws;              ws += (size_t)M * 3 * CC * 2;
    unsigned short* Vt    = (unsigned short*)ws;              ws += (size_t)BB * NH * HD * TT * 2;
    unsigned short* y     = (unsigned short*)ws;

    detect_kernel<<<1, 64, 0, stream>>>(d_in[0], d_in[1], d_in[2], d_in[3], d_in[4], flags);

    convert_bf16<<<(M * CC) / (256 * 8), 256, 0, stream>>>(d_in[0], xb, flags, 0);
    transpose_w<<<dim3(3 * CC / 64, CC / 64), 256, 0, stream>>>(d_in[1], Wqkvt, CC, 3 * CC, flags, 1);
    transpose_w<<<dim3(CC / 64, CC / 64), 256, 0, stream>>>(d_in[3], Wot, CC, CC, flags, 3);

    gemm_mfma<<<dim3(3 * CC / 128, M / 128), 256, 0, stream>>>(
        xb, Wqkvt, d_in[2], qkv, M, 3 * CC, CC, flags, 2, -2);

    transpose_v<<<dim3(TT / 64, BB * NH), 256, 0, stream>>>(qkv, Vt);

    attn_mfma<<<512, 256, 0, stream>>>(qkv, Vt, y);

    gemm_mfma<<<dim3(CC / 128, M / 128), 256, 0, stream>>>(
        y, Wot, d_in[4], d_out, M, CC, CC, flags, 4, 0);
}